// Round 2
// baseline (831.127 us; speedup 1.0000x reference)
//
#include <hip/hip_runtime.h>
#include <math.h>

#define T 16
#define D 2048
#define THREADS 1024
#define EPS 1e-8

// One workgroup per batch. Tile (16x2048 fp32 = 128 KiB) staged in LDS once;
// read input exactly once, write output exactly once.
//
// similar_score[i] = sum_j dot(x_i,x_j)/(n_i*n_j) = (1/n_i) * dot(x_i, s),
// s = sum_j x_j / n_j   (bilinearity) -- avoids the 16x16 pairwise matrix.
__global__ __launch_bounds__(THREADS) void app_tem_kernel(
    const float* __restrict__ in, float* __restrict__ out) {
    __shared__ __align__(16) float xs[T * D];   // 128 KiB batch tile
    __shared__ float  s_vec[D];                 // 8 KiB weighted row-sum
    __shared__ double inv_safe[T];
    __shared__ float  scale[T];                 // (float)(1.0/norm) for output
    __shared__ double score[T];
    __shared__ int    remove_id;

    const int b   = blockIdx.x;
    const int tid = threadIdx.x;
    const float* src = in + (size_t)b * (T * D);

    // ---- 1. stage batch tile into LDS (coalesced float4) ----
    {
        const float4* src4 = (const float4*)src;
        float4* xs4 = (float4*)xs;
        #pragma unroll
        for (int i = 0; i < (T * D / 4) / THREADS; ++i)
            xs4[tid + i * THREADS] = src4[tid + i * THREADS];
    }
    __syncthreads();

    const int wave = tid >> 6;   // 16 waves == 16 rows
    const int lane = tid & 63;

    // ---- 2. row norms: wave w reduces row w (double accumulation) ----
    {
        const float* row = xs + wave * D;
        double acc = 0.0;
        #pragma unroll
        for (int k = 0; k < D / 64; ++k) {
            double v = (double)row[lane + k * 64];
            acc += v * v;
        }
        #pragma unroll
        for (int off = 32; off > 0; off >>= 1)
            acc += __shfl_xor(acc, off, 64);
        if (lane == 0) {
            double nrm = sqrt(acc);
            double sf  = fmax(nrm, (double)EPS);
            inv_safe[wave] = 1.0 / sf;
            scale[wave]    = (float)(1.0 / nrm);  // final normalize uses raw norm
        }
    }
    __syncthreads();

    // ---- 3. s[d] = sum_t x[t][d] * inv_safe[t] (2 columns/thread) ----
    {
        double isf[T];
        #pragma unroll
        for (int t = 0; t < T; ++t) isf[t] = inv_safe[t];
        #pragma unroll
        for (int c = 0; c < D / THREADS; ++c) {
            int d = tid + c * THREADS;
            double acc = 0.0;
            #pragma unroll
            for (int t = 0; t < T; ++t)
                acc += (double)xs[t * D + d] * isf[t];
            s_vec[d] = (float)acc;
        }
    }
    __syncthreads();

    // ---- 4. score[w] = inv_safe[w] * dot(x_w, s) ----
    {
        const float* row = xs + wave * D;
        double acc = 0.0;
        #pragma unroll
        for (int k = 0; k < D / 64; ++k) {
            int d = lane + k * 64;
            acc += (double)row[d] * (double)s_vec[d];
        }
        #pragma unroll
        for (int off = 32; off > 0; off >>= 1)
            acc += __shfl_xor(acc, off, 64);
        if (lane == 0) score[wave] = acc * inv_safe[wave];
    }
    __syncthreads();

    // ---- 5. argmin (first occurrence, like jnp.argmin) ----
    if (tid == 0) {
        double best = score[0];
        int bi = 0;
        #pragma unroll
        for (int t = 1; t < T; ++t)
            if (score[t] < best) { best = score[t]; bi = t; }
        remove_id = bi;
    }
    __syncthreads();

    // ---- 6. write 15 surviving rows, L2-normalized (coalesced float4) ----
    {
        const int rid = remove_id;
        float4* out4 = (float4*)(out + (size_t)b * ((T - 1) * D));
        const float4* xs4 = (const float4*)xs;
        const int total4 = (T - 1) * D / 4;   // 7680
        for (int i = tid; i < total4; i += THREADS) {
            int r  = i >> 9;                  // / (D/4)
            int sr = r + (r >= rid);
            float4 v = xs4[sr * (D / 4) + (i & (D / 4 - 1))];
            float sc = scale[sr];
            v.x *= sc; v.y *= sc; v.z *= sc; v.w *= sc;
            out4[i] = v;
        }
    }
}

extern "C" void kernel_launch(void* const* d_in, const int* in_sizes, int n_in,
                              void* d_out, int out_size, void* d_ws, size_t ws_size,
                              hipStream_t stream) {
    const float* in  = (const float*)d_in[0];
    float* out = (float*)d_out;
    const int B = in_sizes[0] / (T * D);   // 4096
    app_tem_kernel<<<B, THREADS, 0, stream>>>(in, out);
}